// Round 1
// baseline (57.740 us; speedup 1.0000x reference)
//
#include <hip/hip_runtime.h>
#include <math.h>

#define BLOCK 256

struct V2 { float x, y; };

__device__ __forceinline__ void box_corners(float x, float y, float hx, float hy,
                                            float c, float s, V2* out) {
    // local corners (hx,hy), (-hx,hy), (-hx,-hy), (hx,-hy)  -- CCW (matches ref)
    const float cx = c * hx, sx = s * hx, cy = c * hy, sy = s * hy;
    out[0].x = x + cx - sy; out[0].y = y + sx + cy;
    out[1].x = x - cx - sy; out[1].y = y - sx + cy;
    out[2].x = x - cx + sy; out[2].y = y - sx - cy;
    out[3].x = x + cx + sy; out[3].y = y + sx - cy;
}

// Intersection area of two convex CCW quads via Sutherland-Hodgman clipping.
__device__ float quad_inter_area(const V2* __restrict__ A, const V2* __restrict__ B) {
    V2 poly[8];
    int n = 4;
    for (int i = 0; i < 4; ++i) poly[i] = A[i];

    for (int k = 0; k < 4; ++k) {
        const V2 c1 = B[k];
        const V2 c2 = B[(k + 1) & 3];
        const float ex = c2.x - c1.x, ey = c2.y - c1.y;
        float d[8];
        for (int i = 0; i < n; ++i)
            d[i] = ex * (poly[i].y - c1.y) - ey * (poly[i].x - c1.x);
        V2 outp[8];
        int m = 0;
        for (int i = 0; i < n; ++i) {
            const int j = (i + 1 == n) ? 0 : i + 1;
            const float dp = d[i], dq = d[j];
            const bool inp = (dp >= 0.f), inq = (dq >= 0.f);
            if (inp) outp[m++] = poly[i];
            if (inp != inq) {
                const float t = dp / (dp - dq);
                outp[m].x = poly[i].x + t * (poly[j].x - poly[i].x);
                outp[m].y = poly[i].y + t * (poly[j].y - poly[i].y);
                ++m;
            }
        }
        n = m;
        if (n < 3) return 0.f;
        for (int i = 0; i < n; ++i) poly[i] = outp[i];
    }

    float area = 0.f;
    for (int i = 0; i < n; ++i) {
        const int j = (i + 1 == n) ? 0 : i + 1;
        area += poly[i].x * poly[j].y - poly[i].y * poly[j].x;
    }
    return 0.5f * fabsf(area);
}

__global__ __launch_bounds__(BLOCK) void iou_row_kernel(
    const float* __restrict__ iou_pred,
    const float* __restrict__ box_pred,
    const float* __restrict__ box_gt,
    float* __restrict__ rowloss,
    int M)
{
    const int i = blockIdx.x;
    // pred box (wave-uniform)
    const float ax   = box_pred[i * 7 + 0];
    const float ay   = box_pred[i * 7 + 1];
    const float adx  = box_pred[i * 7 + 3];
    const float ady  = box_pred[i * 7 + 4];
    const float ayaw = box_pred[i * 7 + 6];
    const float ac = cosf(ayaw), as_ = sinf(ayaw);
    const float ahx = 0.5f * adx, ahy = 0.5f * ady;
    const float area_a = adx * ady;
    const float ra2 = ahx * ahx + ahy * ahy;   // squared circumradius
    V2 CA[4];
    box_corners(ax, ay, ahx, ahy, ac, as_, CA);

    float maxiou = 0.f;
    for (int j = threadIdx.x; j < M; j += BLOCK) {
        const float bx   = box_gt[j * 7 + 0];
        const float by   = box_gt[j * 7 + 1];
        const float bdx  = box_gt[j * 7 + 3];
        const float bdy  = box_gt[j * 7 + 4];
        const float byaw = box_gt[j * 7 + 6];
        const float bhx = 0.5f * bdx, bhy = 0.5f * bdy;
        const float rb2 = bhx * bhx + bhy * bhy;
        const float dx = bx - ax, dy = by - ay;
        const float d2 = dx * dx + dy * dy;
        // (ra+rb)^2 = ra2 + rb2 + 2*sqrt(ra2*rb2)
        const float rr = ra2 + rb2 + 2.f * sqrtf(ra2 * rb2);
        float inter = 0.f;
        if (d2 <= rr) {
            const float bc = cosf(byaw), bs = sinf(byaw);
            V2 CB[4];
            box_corners(bx, by, bhx, bhy, bc, bs, CB);
            inter = quad_inter_area(CA, CB);
        }
        const float area_b = bdx * bdy;
        const float uni = fmaxf(area_a + area_b - inter, 1e-8f);
        maxiou = fmaxf(maxiou, inter / uni);
    }

    __shared__ float sred[BLOCK];
    sred[threadIdx.x] = maxiou;
    __syncthreads();
    for (int s = BLOCK / 2; s > 0; s >>= 1) {
        if (threadIdx.x < s)
            sred[threadIdx.x] = fmaxf(sred[threadIdx.x], sred[threadIdx.x + s]);
        __syncthreads();
    }
    if (threadIdx.x == 0) {
        const float target = 2.f * sred[0] - 1.f;
        rowloss[i] = fabsf(iou_pred[i] - target);
    }
}

__global__ __launch_bounds__(256) void loss_reduce_kernel(
    const float* __restrict__ rowloss,
    const int* __restrict__ ntp,
    float* __restrict__ out,
    int N)
{
    __shared__ float s[256];
    float acc = 0.f;
    for (int i = threadIdx.x; i < N; i += 256) acc += rowloss[i];
    s[threadIdx.x] = acc;
    __syncthreads();
    for (int k = 128; k > 0; k >>= 1) {
        if (threadIdx.x < k) s[threadIdx.x] += s[threadIdx.x + k];
        __syncthreads();
    }
    if (threadIdx.x == 0) out[0] = s[0] / ((float)ntp[0] + 1e-4f);
}

extern "C" void kernel_launch(void* const* d_in, const int* in_sizes, int n_in,
                              void* d_out, int out_size, void* d_ws, size_t ws_size,
                              hipStream_t stream) {
    const float* iou_pred = (const float*)d_in[0];
    const float* box_pred = (const float*)d_in[1];
    const float* box_gt   = (const float*)d_in[2];
    const int*   ntp      = (const int*)d_in[3];
    float* out     = (float*)d_out;
    float* rowloss = (float*)d_ws;

    const int N = in_sizes[0];        // iou_pred is (N,1)
    const int M = in_sizes[2] / 7;    // box_gt is (M,7)

    iou_row_kernel<<<N, BLOCK, 0, stream>>>(iou_pred, box_pred, box_gt, rowloss, M);
    loss_reduce_kernel<<<1, 256, 0, stream>>>(rowloss, ntp, out, N);
}

// Round 2
// 16.180 us; speedup vs baseline: 3.5686x; 3.5686x over previous
//
#include <hip/hip_runtime.h>
#include <math.h>

#define BLOCK 256
#define PSTRIDE 19   // V2 units per thread clip region: P@0..8, Q@9..17, +1 pad
                     // bank(slot e, thread t) = (38t + 2e) % 32 -> only t, t+16
                     // collide (2-way, free per m136)

struct __align__(8) V2 { float x, y; };

__device__ __forceinline__ void box_corners(float x, float y, float hx, float hy,
                                            float c, float s, V2* out) {
    // CCW corners (matches reference _corners order)
    const float cx = c * hx, sx = s * hx, cy = c * hy, sy = s * hy;
    out[0].x = x + cx - sy; out[0].y = y + sx + cy;
    out[1].x = x - cx - sy; out[1].y = y - sx + cy;
    out[2].x = x - cx + sy; out[2].y = y - sx - cy;
    out[3].x = x + cx + sy; out[3].y = y + sx - cy;
}

// Sutherland-Hodgman clip of quad A by quad B (both convex CCW), LDS ping-pong.
__device__ float quad_inter_area(V2* __restrict__ buf, const V2* A, const V2* B) {
    int pO = 0, qO = 9;
    #pragma unroll
    for (int i = 0; i < 4; ++i) buf[pO + i] = A[i];
    int n = 4;

    #pragma unroll
    for (int k = 0; k < 4; ++k) {
        const V2 c1 = B[k];
        const V2 c2 = B[(k + 1) & 3];
        const float ex = c2.x - c1.x, ey = c2.y - c1.y;
        int m = 0;
        V2 vp = buf[pO + n - 1];
        float dp = ex * (vp.y - c1.y) - ey * (vp.x - c1.x);
        for (int i = 0; i < n; ++i) {
            const V2 vc = buf[pO + i];
            const float dc = ex * (vc.y - c1.y) - ey * (vc.x - c1.x);
            const bool inc = (dc >= 0.f), inp = (dp >= 0.f);
            if (inc != inp) {
                const float t = dp / (dp - dc);
                V2 X; X.x = vp.x + t * (vc.x - vp.x); X.y = vp.y + t * (vc.y - vp.y);
                if (m < 9) buf[qO + m] = X;
                ++m;
            }
            if (inc) {
                if (m < 9) buf[qO + m] = vc;
                ++m;
            }
            vp = vc; dp = dc;
        }
        n = (m < 9) ? m : 9;
        if (n < 3) return 0.f;
        const int t_ = pO; pO = qO; qO = t_;
    }

    const V2 v0 = buf[pO];
    V2 vp = v0;
    float area = 0.f;
    for (int i = 1; i < n; ++i) {
        const V2 vc = buf[pO + i];
        area += vp.x * vc.y - vp.y * vc.x;
        vp = vc;
    }
    area += vp.x * v0.y - vp.y * v0.x;
    return 0.5f * fabsf(area);
}

__global__ __launch_bounds__(BLOCK) void iou_row_kernel(
    const float* __restrict__ iou_pred,
    const float* __restrict__ box_pred,
    const float* __restrict__ box_gt,
    float* __restrict__ rowloss,
    int M)
{
    __shared__ int s_n;
    __shared__ int s_idx[512];
    __shared__ float s_red[BLOCK];
    __shared__ V2  s_poly[64 * PSTRIDE];   // clip buffers, wave 0 only

    const int tid = threadIdx.x;
    const int i = blockIdx.x;
    if (tid == 0) s_n = 0;

    // pred box (wave-uniform)
    const float ax   = box_pred[i * 7 + 0];
    const float ay   = box_pred[i * 7 + 1];
    const float adx  = box_pred[i * 7 + 3];
    const float ady  = box_pred[i * 7 + 4];
    const float ayaw = box_pred[i * 7 + 6];
    const float ahx = 0.5f * adx, ahy = 0.5f * ady;
    const float area_a = adx * ady;
    const float ra = sqrtf(ahx * ahx + ahy * ahy);
    V2 CA[4];
    box_corners(ax, ay, ahx, ahy, cosf(ayaw), sinf(ayaw), CA);
    __syncthreads();

    // phase 1: circumradius reject + compaction (no trig needed)
    for (int j = tid; j < M; j += BLOCK) {
        const float bx  = box_gt[j * 7 + 0];
        const float by  = box_gt[j * 7 + 1];
        const float bdx = box_gt[j * 7 + 3];
        const float bdy = box_gt[j * 7 + 4];
        const float rb = 0.5f * sqrtf(bdx * bdx + bdy * bdy);
        const float dx = bx - ax, dy = by - ay;
        const float rr = ra + rb;
        if (dx * dx + dy * dy <= rr * rr) {
            const int pos = atomicAdd(&s_n, 1);
            if (pos < 512) s_idx[pos] = j;
        }
    }
    __syncthreads();

    // phase 2: wave 0 clips the survivors (SIMD-parallel, LDS buffers)
    float mymax = 0.f;
    if (tid < 64) {
        V2* buf = &s_poly[tid * PSTRIDE];
        const int ns = (s_n < 512) ? s_n : 512;
        for (int k = tid; k < ns; k += 64) {
            const int j = s_idx[k];
            const float bx   = box_gt[j * 7 + 0];
            const float by   = box_gt[j * 7 + 1];
            const float bdx  = box_gt[j * 7 + 3];
            const float bdy  = box_gt[j * 7 + 4];
            const float byaw = box_gt[j * 7 + 6];
            V2 CB[4];
            box_corners(bx, by, 0.5f * bdx, 0.5f * bdy, cosf(byaw), sinf(byaw), CB);
            const float inter = quad_inter_area(buf, CA, CB);
            const float uni = fmaxf(area_a + bdx * bdy - inter, 1e-8f);
            mymax = fmaxf(mymax, inter / uni);
        }
    }

    s_red[tid] = mymax;
    __syncthreads();
    for (int s = BLOCK / 2; s > 0; s >>= 1) {
        if (tid < s) s_red[tid] = fmaxf(s_red[tid], s_red[tid + s]);
        __syncthreads();
    }
    if (tid == 0) {
        const float target = 2.f * s_red[0] - 1.f;
        rowloss[i] = fabsf(iou_pred[i] - target);
    }
}

__global__ __launch_bounds__(256) void loss_reduce_kernel(
    const float* __restrict__ rowloss,
    const int* __restrict__ ntp,
    float* __restrict__ out,
    int N)
{
    __shared__ float s[256];
    float acc = 0.f;
    for (int i = threadIdx.x; i < N; i += 256) acc += rowloss[i];
    s[threadIdx.x] = acc;
    __syncthreads();
    for (int k = 128; k > 0; k >>= 1) {
        if (threadIdx.x < k) s[threadIdx.x] += s[threadIdx.x + k];
        __syncthreads();
    }
    if (threadIdx.x == 0) out[0] = s[0] / ((float)ntp[0] + 1e-4f);
}

extern "C" void kernel_launch(void* const* d_in, const int* in_sizes, int n_in,
                              void* d_out, int out_size, void* d_ws, size_t ws_size,
                              hipStream_t stream) {
    const float* iou_pred = (const float*)d_in[0];
    const float* box_pred = (const float*)d_in[1];
    const float* box_gt   = (const float*)d_in[2];
    const int*   ntp      = (const int*)d_in[3];
    float* out     = (float*)d_out;
    float* rowloss = (float*)d_ws;

    const int N = in_sizes[0];        // iou_pred is (N,1)
    const int M = in_sizes[2] / 7;    // box_gt is (M,7)

    iou_row_kernel<<<N, BLOCK, 0, stream>>>(iou_pred, box_pred, box_gt, rowloss, M);
    loss_reduce_kernel<<<1, 256, 0, stream>>>(rowloss, ntp, out, N);
}